// Round 22
// baseline (48.990 us; speedup 1.0000x reference)
//
#include <hip/hip_runtime.h>
#include <cstdint>

typedef unsigned long long u64;
typedef _Float16 half8 __attribute__((ext_vector_type(8)));
typedef float f32x4 __attribute__((ext_vector_type(4)));

static constexpr int Dd = 128;
static constexpr float EPSf = 1e-6f;
static constexpr float MARGINf = 1.0f;
static constexpr float BIGf = 3.0e38f;

// Monotonic map fp32 -> u32 (total order matching float compare).
__device__ __forceinline__ unsigned fkey(float f) {
  unsigned b = __float_as_uint(f);
  return (b & 0x80000000u) ? ~b : (b | 0x80000000u);
}

// Block = 16 rows. Packed fragment-major fp16:
// half idx = ((T*4+ks)*64 + lg*16 + r15)*8 + h ; T=row>>4, k=ks*32+lg*8+h.
__global__ __launch_bounds__(256) void k_prep(const float* __restrict__ E,
                                              _Float16* __restrict__ Ehp,
                                              float* __restrict__ normf) {
  __shared__ float part[4][16];
  const int t = threadIdx.x;
  const int b = blockIdx.x;
  const int ks = t >> 6, r15 = t & 15;
  const int lg = (t >> 4) & 3;
  const float* src = E + (size_t)(b * 16 + r15) * Dd + ks * 32 + lg * 8;
  float4 v0 = *(const float4*)src;
  float4 v1 = *(const float4*)(src + 4);
  half8 hv;
  hv[0] = (_Float16)v0.x; hv[1] = (_Float16)v0.y;
  hv[2] = (_Float16)v0.z; hv[3] = (_Float16)v0.w;
  hv[4] = (_Float16)v1.x; hv[5] = (_Float16)v1.y;
  hv[6] = (_Float16)v1.z; hv[7] = (_Float16)v1.w;
  *(half8*)((char*)Ehp + (size_t)b * 4096 + t * 16) = hv;
  float s = v0.x * v0.x + v0.y * v0.y + v0.z * v0.z + v0.w * v0.w +
            v1.x * v1.x + v1.y * v1.y + v1.z * v1.z + v1.w * v1.w;
  s += __shfl_xor(s, 16);
  s += __shfl_xor(s, 32);
  if (((t >> 4) & 3) == 0) part[ks][r15] = s;
  __syncthreads();
  if (t < 16) normf[b * 16 + t] = part[0][t] + part[1][t] + part[2][t] + part[3][t];
}

// Streamer at 512 threads / 8 waves: wave-tile 64i x 16j, acc shrinks to
// 16 VGPR -> launch_bounds(512,4) targets the <=128-VGPR class => 16 waves/CU
// (4/SIMD), doubling latency hiding vs every prior 8-wave/CU variant.
// Structure otherwise identical to the proven R15/R20 kernel.
__global__ __launch_bounds__(512, 4) void k_gemm(const _Float16* __restrict__ Ehp,
                                                 const float* __restrict__ normf,
                                                 const int* __restrict__ lab,
                                                 u64* __restrict__ posPart,
                                                 u64* __restrict__ negPart) {
  __shared__ __align__(16) char Jb[2][16384];  // j dbuf, 64 rows each
  __shared__ __align__(16) float njs[1024];
  __shared__ __align__(16) int ljs[1024];

  const int t = threadIdx.x;
  const int w = t >> 6, l = t & 63;
  const int lane15 = l & 15, lg = l >> 4;
  const int iw = w & 1, jw = w >> 1;  // 2 i-groups x 4 j-groups
  const int panel = blockIdx.x;       // 64 i-panels
  const int strip = blockIdx.y;       // 8 j-strips
  const int ibase = panel * 128;
  const int jbase = strip * 1024;
  const char* jsrc = (const char*)Ehp + (size_t)(jbase >> 4) * 4096;

  // ---- prologue: stage j-tile0 + strip norms/labels; i-frags -> registers ----
  #pragma unroll
  for (int q = 0; q < 2; ++q)
    *(half8*)(Jb[0] + q * 8192 + t * 16) = *(const half8*)(jsrc + q * 8192 + t * 16);
  *(float2*)&njs[t * 2] = *(const float2*)&normf[jbase + t * 2];
  *(int2*)&ljs[t * 2] = *(const int2*)&lab[jbase + t * 2];

  const int gi0 = ibase + iw * 64;
  half8 bf[4][4];  // 64 VGPR, reused across all 16 tiles
  #pragma unroll
  for (int it = 0; it < 4; ++it)
    #pragma unroll
    for (int ks = 0; ks < 4; ++ks)
      bf[it][ks] = *(const half8*)(Ehp + ((size_t)((gi0 >> 4) + it) * 4 + ks) * 512 +
                                   (size_t)l * 8);
  int li[4];
  #pragma unroll
  for (int it = 0; it < 4; ++it) li[it] = lab[gi0 + it * 16 + lane15];
  __syncthreads();

  float bp[4] = {-BIGf, -BIGf, -BIGf, -BIGf};
  float bn[4] = {BIGf, BIGf, BIGf, BIGf};

  for (int tile = 0; tile < 16; ++tile) {
    const int cur = tile & 1;
    half8 sreg[2];
    if (tile < 15) {  // T14: issue next tile's loads; hide under compute
      const char* s = jsrc + (size_t)(tile + 1) * 16384;
      #pragma unroll
      for (int q = 0; q < 2; ++q) sreg[q] = *(const half8*)(s + q * 8192 + t * 16);
    }

    // ---- compute: wave-tile 64i x 16j; aj from LDS (4 reads/tile) ----
    f32x4 acc[4];
    #pragma unroll
    for (int b = 0; b < 4; ++b) acc[b] = (f32x4){0.f, 0.f, 0.f, 0.f};

    #pragma unroll
    for (int ks = 0; ks < 4; ++ks) {
      half8 aj = *(const half8*)(Jb[cur] + (jw * 4 + ks) * 1024 + l * 16);
      __builtin_amdgcn_s_setprio(1);
      #pragma unroll
      for (int it = 0; it < 4; ++it)
        acc[it] = __builtin_amdgcn_mfma_f32_16x16x32_f16(aj, bf[it][ks], acc[it], 0, 0, 0);
      __builtin_amdgcn_s_setprio(0);
    }

    // ---- masked pos/neg epilogue (absmax-0-proven semantics) ----
    {
      const int jr0 = tile * 64 + jw * 16 + lg * 4;  // strip-local j of reg 0
      const float4 nj4 = *(const float4*)&njs[jr0];
      const int4 lj4 = *(const int4*)&ljs[jr0];
      #pragma unroll
      for (int it = 0; it < 4; ++it) {
        float c0 = fmaf(acc[it][0], -2.0f, nj4.x);
        float c1 = fmaf(acc[it][1], -2.0f, nj4.y);
        float c2 = fmaf(acc[it][2], -2.0f, nj4.z);
        float c3 = fmaf(acc[it][3], -2.0f, nj4.w);
        c0 = __uint_as_float((__float_as_uint(c0) & 0xFFFFFC00u) | (unsigned)(jr0 + 0));
        c1 = __uint_as_float((__float_as_uint(c1) & 0xFFFFFC00u) | (unsigned)(jr0 + 1));
        c2 = __uint_as_float((__float_as_uint(c2) & 0xFFFFFC00u) | (unsigned)(jr0 + 2));
        c3 = __uint_as_float((__float_as_uint(c3) & 0xFFFFFC00u) | (unsigned)(jr0 + 3));
        bool s0 = (lj4.x == li[it]), s1 = (lj4.y == li[it]);
        bool s2 = (lj4.z == li[it]), s3 = (lj4.w == li[it]);
        float p0 = s0 ? c0 : -BIGf, p1 = s1 ? c1 : -BIGf;
        float p2 = s2 ? c2 : -BIGf, p3 = s3 ? c3 : -BIGf;
        float n0 = s0 ? BIGf : c0, n1 = s1 ? BIGf : c1;
        float n2 = s2 ? BIGf : c2, n3 = s3 ? BIGf : c3;
        bp[it] = fmaxf(bp[it], fmaxf(fmaxf(p0, p1), fmaxf(p2, p3)));
        bn[it] = fminf(bn[it], fminf(fminf(n0, n1), fminf(n2, n3)));
      }
    }

    __syncthreads();  // all waves done reading Jb[cur]
    if (tile < 15) {
      #pragma unroll
      for (int q = 0; q < 2; ++q)
        *(half8*)(Jb[cur ^ 1] + q * 8192 + t * 16) = sreg[q];
    }
    __syncthreads();  // next tile visible
  }

  // merge the 4 lg-lanes (same i, disjoint j), plain partial stores
  #pragma unroll
  for (int it = 0; it < 4; ++it) {
    bp[it] = fmaxf(bp[it], __shfl_xor(bp[it], 16));
    bp[it] = fmaxf(bp[it], __shfl_xor(bp[it], 32));
    bn[it] = fminf(bn[it], __shfl_xor(bn[it], 16));
    bn[it] = fminf(bn[it], __shfl_xor(bn[it], 32));
  }
  if (l < 16) {
    const int slot = strip * 4 + jw;  // 32 slots
    #pragma unroll
    for (int it = 0; it < 4; ++it) {
      int gi = ibase + iw * 64 + it * 16 + lane15;
      unsigned gjp = (unsigned)jbase + (__float_as_uint(bp[it]) & 1023u);
      unsigned gjn = (unsigned)jbase + (__float_as_uint(bn[it]) & 1023u);
      posPart[(size_t)slot * 8192 + gi] =
          ((u64)fkey(bp[it]) << 32) | (u64)(0xFFFFFFFFu - gjp);
      negPart[(size_t)slot * 8192 + gi] = ((u64)fkey(bn[it]) << 32) | (u64)gjn;
    }
  }
}

// One wave per row: merge 32 partial slots, exact fp32 triplet term.
__global__ __launch_bounds__(256) void k_final(const float* __restrict__ E,
                                               const u64* __restrict__ posPart,
                                               const u64* __restrict__ negPart,
                                               float* __restrict__ rowLoss) {
  int i = (blockIdx.x * 256 + threadIdx.x) >> 6;
  int l = threadIdx.x & 63;
  u64 pp = 0ull, np = ~0ull;
  if (l < 32) {
    pp = posPart[(size_t)l * 8192 + i];
    np = negPart[(size_t)l * 8192 + i];
  }
  #pragma unroll
  for (int off = 1; off < 64; off <<= 1) {
    u64 a = __shfl_xor(pp, off);
    u64 b = __shfl_xor(np, off);
    pp = pp > a ? pp : a;
    np = np < b ? np : b;
  }
  int jp = (int)((0xFFFFFFFFu - (unsigned)(pp & 0xFFFFFFFFull)) & 8191u);
  int jn = (int)((unsigned)(np & 0xFFFFFFFFull) & 8191u);
  float2 a = *(const float2*)(E + (size_t)i * Dd + l * 2);
  float2 p = *(const float2*)(E + (size_t)jp * Dd + l * 2);
  float2 n = *(const float2*)(E + (size_t)jn * Dd + l * 2);
  float dx = a.x - p.x + EPSf, dy = a.y - p.y + EPSf;
  float sap = dx * dx + dy * dy;
  dx = a.x - n.x + EPSf;
  dy = a.y - n.y + EPSf;
  float san = dx * dx + dy * dy;
  #pragma unroll
  for (int off = 32; off; off >>= 1) {
    sap += __shfl_xor(sap, off);
    san += __shfl_xor(san, off);
  }
  if (l == 0) rowLoss[i] = fmaxf(sqrtf(sap) - sqrtf(san) + MARGINf, 0.0f);
}

// Deterministic tree reduction -> mean.
__global__ __launch_bounds__(256) void k_reduce(const float* __restrict__ rowLoss,
                                                float* __restrict__ out) {
  __shared__ float s[256];
  int t = threadIdx.x;
  float sum = 0.f;
  for (int q = 0; q < 32; ++q) sum += rowLoss[t + 256 * q];
  s[t] = sum;
  __syncthreads();
  for (int off = 128; off; off >>= 1) {
    if (t < off) s[t] += s[t + off];
    __syncthreads();
  }
  if (t == 0) out[0] = s[0] * (1.0f / 8192.0f);
}

extern "C" void kernel_launch(void* const* d_in, const int* in_sizes, int n_in,
                              void* d_out, int out_size, void* d_ws, size_t ws_size,
                              hipStream_t stream) {
  const float* E = (const float*)d_in[0];
  const int* lab = (const int*)d_in[1];
  float* out = (float*)d_out;

  char* wsp = (char*)d_ws;
  u64* posPart = (u64*)wsp;                         // 32*8192*8 = 2 MB
  u64* negPart = (u64*)(wsp + (2048 << 10));        // 2 MB
  float* normf = (float*)(wsp + (4096 << 10));      // 32 KB
  float* rowLoss = (float*)(wsp + (4128 << 10));    // 32 KB
  _Float16* Ehp = (_Float16*)(wsp + (4160 << 10));  // 2 MB packed frags

  k_prep<<<512, 256, 0, stream>>>(E, Ehp, normf);
  k_gemm<<<dim3(64, 8), 512, 0, stream>>>(Ehp, normf, lab, posPart, negPart);
  k_final<<<2048, 256, 0, stream>>>(E, posPart, negPart, rowLoss);
  k_reduce<<<1, 256, 0, stream>>>(rowLoss, out);
}

// Round 23
// 43.231 us; speedup vs baseline: 1.1332x; 1.1332x over previous
//
#include <hip/hip_runtime.h>
#include <cstdint>

typedef unsigned long long u64;
typedef _Float16 half8 __attribute__((ext_vector_type(8)));
typedef float f32x4 __attribute__((ext_vector_type(4)));

static constexpr int Dd = 128;
static constexpr float EPSf = 1e-6f;
static constexpr float MARGINf = 1.0f;
static constexpr float BIGf = 3.0e38f;

// Monotonic map fp32 -> u32 (total order matching float compare).
__device__ __forceinline__ unsigned fkey(float f) {
  unsigned b = __float_as_uint(f);
  return (b & 0x80000000u) ? ~b : (b | 0x80000000u);
}

// Block = 16 rows. Packed fragment-major fp16:
// half idx = ((T*4+ks)*64 + lg*16 + r15)*8 + h ; T=row>>4, k=ks*32+lg*8+h.
__global__ __launch_bounds__(256) void k_prep(const float* __restrict__ E,
                                              _Float16* __restrict__ Ehp,
                                              float* __restrict__ normf) {
  __shared__ float part[4][16];
  const int t = threadIdx.x;
  const int b = blockIdx.x;
  const int ks = t >> 6, r15 = t & 15;
  const int lg = (t >> 4) & 3;
  const float* src = E + (size_t)(b * 16 + r15) * Dd + ks * 32 + lg * 8;
  float4 v0 = *(const float4*)src;
  float4 v1 = *(const float4*)(src + 4);
  half8 hv;
  hv[0] = (_Float16)v0.x; hv[1] = (_Float16)v0.y;
  hv[2] = (_Float16)v0.z; hv[3] = (_Float16)v0.w;
  hv[4] = (_Float16)v1.x; hv[5] = (_Float16)v1.y;
  hv[6] = (_Float16)v1.z; hv[7] = (_Float16)v1.w;
  *(half8*)((char*)Ehp + (size_t)b * 4096 + t * 16) = hv;
  float s = v0.x * v0.x + v0.y * v0.y + v0.z * v0.z + v0.w * v0.w +
            v1.x * v1.x + v1.y * v1.y + v1.z * v1.z + v1.w * v1.w;
  s += __shfl_xor(s, 16);
  s += __shfl_xor(s, 32);
  if (((t >> 4) & 3) == 0) part[ks][r15] = s;
  __syncthreads();
  if (t < 16) normf[b * 16 + t] = part[0][t] + part[1][t] + part[2][t] + part[3][t];
}

// Streamer: i-frags register-resident (loaded once from packed Ehp); 1024-j
// strip as 16 double-buffered 16KB tiles; T14 prefetch; setprio around MFMA
// clusters. launch_bounds(256,2) -> no spills. Best-measured configuration
// (43.3us R15, 43.4us R20): 540 TF effective, ~= the 2-phase-class measured
// structural ceiling (m233); deeper requires the 8-phase counted-vmcnt
// co-design not reachable incrementally from this template.
__global__ __launch_bounds__(256, 2) void k_gemm(const _Float16* __restrict__ Ehp,
                                                 const float* __restrict__ normf,
                                                 const int* __restrict__ lab,
                                                 u64* __restrict__ posPart,
                                                 u64* __restrict__ negPart) {
  __shared__ __align__(16) char Jb[2][16384];  // j dbuf, 64 rows each
  __shared__ __align__(16) float njs[1024];
  __shared__ __align__(16) int ljs[1024];

  const int t = threadIdx.x;
  const int w = t >> 6, l = t & 63;
  const int lane15 = l & 15, lg = l >> 4;
  const int iw = w & 1, jw = w >> 1;  // 2 i-groups x 2 j-groups
  const int panel = blockIdx.x;       // 64 i-panels
  const int strip = blockIdx.y;       // 8 j-strips
  const int ibase = panel * 128;
  const int jbase = strip * 1024;
  const char* jsrc = (const char*)Ehp + (size_t)(jbase >> 4) * 4096;

  // ---- prologue: stage j-tile0 + strip norms/labels; i-frags -> registers ----
  #pragma unroll
  for (int q = 0; q < 4; ++q)
    *(half8*)(Jb[0] + q * 4096 + t * 16) = *(const half8*)(jsrc + q * 4096 + t * 16);
  *(float4*)&njs[t * 4] = *(const float4*)&normf[jbase + t * 4];
  *(int4*)&ljs[t * 4] = *(const int4*)&lab[jbase + t * 4];

  const int gi0 = ibase + iw * 64;
  half8 bf[4][4];  // 64 VGPR, reused across all 16 tiles
  #pragma unroll
  for (int it = 0; it < 4; ++it)
    #pragma unroll
    for (int ks = 0; ks < 4; ++ks)
      bf[it][ks] = *(const half8*)(Ehp + ((size_t)((gi0 >> 4) + it) * 4 + ks) * 512 +
                                   (size_t)l * 8);
  int li[4];
  #pragma unroll
  for (int it = 0; it < 4; ++it) li[it] = lab[gi0 + it * 16 + lane15];
  __syncthreads();

  float bp[4] = {-BIGf, -BIGf, -BIGf, -BIGf};
  float bn[4] = {BIGf, BIGf, BIGf, BIGf};

  for (int tile = 0; tile < 16; ++tile) {
    const int cur = tile & 1;
    half8 sreg[4];
    if (tile < 15) {  // T14: issue next tile's loads; hide under compute
      const char* s = jsrc + (size_t)(tile + 1) * 16384;
      #pragma unroll
      for (int q = 0; q < 4; ++q) sreg[q] = *(const half8*)(s + q * 4096 + t * 16);
    }

    // ---- compute: wave-tile 64i x 32j; only aj from LDS (8 reads/tile) ----
    f32x4 acc[2][4];
    #pragma unroll
    for (int a = 0; a < 2; ++a)
      #pragma unroll
      for (int b = 0; b < 4; ++b) acc[a][b] = (f32x4){0.f, 0.f, 0.f, 0.f};

    #pragma unroll
    for (int ks = 0; ks < 4; ++ks) {
      half8 aj[2];
      #pragma unroll
      for (int jt = 0; jt < 2; ++jt)
        aj[jt] = *(const half8*)(Jb[cur] + ((jw * 2 + jt) * 4 + ks) * 1024 + l * 16);
      __builtin_amdgcn_s_setprio(1);
      #pragma unroll
      for (int jt = 0; jt < 2; ++jt)
        #pragma unroll
        for (int it = 0; it < 4; ++it)
          acc[jt][it] = __builtin_amdgcn_mfma_f32_16x16x32_f16(aj[jt], bf[it][ks], acc[jt][it], 0, 0, 0);
      __builtin_amdgcn_s_setprio(0);
    }

    // ---- masked pos/neg epilogue (absmax-0-proven semantics) ----
    #pragma unroll
    for (int jt = 0; jt < 2; ++jt) {
      const int jr0 = tile * 64 + jw * 32 + jt * 16 + lg * 4;  // strip-local
      const float4 nj4 = *(const float4*)&njs[jr0];
      const int4 lj4 = *(const int4*)&ljs[jr0];
      #pragma unroll
      for (int it = 0; it < 4; ++it) {
        float c0 = fmaf(acc[jt][it][0], -2.0f, nj4.x);
        float c1 = fmaf(acc[jt][it][1], -2.0f, nj4.y);
        float c2 = fmaf(acc[jt][it][2], -2.0f, nj4.z);
        float c3 = fmaf(acc[jt][it][3], -2.0f, nj4.w);
        c0 = __uint_as_float((__float_as_uint(c0) & 0xFFFFFC00u) | (unsigned)(jr0 + 0));
        c1 = __uint_as_float((__float_as_uint(c1) & 0xFFFFFC00u) | (unsigned)(jr0 + 1));
        c2 = __uint_as_float((__float_as_uint(c2) & 0xFFFFFC00u) | (unsigned)(jr0 + 2));
        c3 = __uint_as_float((__float_as_uint(c3) & 0xFFFFFC00u) | (unsigned)(jr0 + 3));
        bool s0 = (lj4.x == li[it]), s1 = (lj4.y == li[it]);
        bool s2 = (lj4.z == li[it]), s3 = (lj4.w == li[it]);
        float p0 = s0 ? c0 : -BIGf, p1 = s1 ? c1 : -BIGf;
        float p2 = s2 ? c2 : -BIGf, p3 = s3 ? c3 : -BIGf;
        float n0 = s0 ? BIGf : c0, n1 = s1 ? BIGf : c1;
        float n2 = s2 ? BIGf : c2, n3 = s3 ? BIGf : c3;
        bp[it] = fmaxf(bp[it], fmaxf(fmaxf(p0, p1), fmaxf(p2, p3)));
        bn[it] = fminf(bn[it], fminf(fminf(n0, n1), fminf(n2, n3)));
      }
    }

    __syncthreads();  // all waves done reading Jb[cur]
    if (tile < 15) {
      #pragma unroll
      for (int q = 0; q < 4; ++q)
        *(half8*)(Jb[cur ^ 1] + q * 4096 + t * 16) = sreg[q];
    }
    __syncthreads();  // next tile visible
  }

  // merge the 4 lg-lanes (same i, disjoint j), plain partial stores
  #pragma unroll
  for (int it = 0; it < 4; ++it) {
    bp[it] = fmaxf(bp[it], __shfl_xor(bp[it], 16));
    bp[it] = fmaxf(bp[it], __shfl_xor(bp[it], 32));
    bn[it] = fminf(bn[it], __shfl_xor(bn[it], 16));
    bn[it] = fminf(bn[it], __shfl_xor(bn[it], 32));
  }
  if (l < 16) {
    const int slot = strip * 2 + jw;
    #pragma unroll
    for (int it = 0; it < 4; ++it) {
      int gi = ibase + iw * 64 + it * 16 + lane15;
      unsigned gjp = (unsigned)jbase + (__float_as_uint(bp[it]) & 1023u);
      unsigned gjn = (unsigned)jbase + (__float_as_uint(bn[it]) & 1023u);
      posPart[(size_t)slot * 8192 + gi] =
          ((u64)fkey(bp[it]) << 32) | (u64)(0xFFFFFFFFu - gjp);
      negPart[(size_t)slot * 8192 + gi] = ((u64)fkey(bn[it]) << 32) | (u64)gjn;
    }
  }
}

// One wave per row: merge 16 partial slots, exact fp32 triplet term.
__global__ __launch_bounds__(256) void k_final(const float* __restrict__ E,
                                               const u64* __restrict__ posPart,
                                               const u64* __restrict__ negPart,
                                               float* __restrict__ rowLoss) {
  int i = (blockIdx.x * 256 + threadIdx.x) >> 6;
  int l = threadIdx.x & 63;
  u64 pp = 0ull, np = ~0ull;
  if (l < 16) {
    pp = posPart[(size_t)l * 8192 + i];
    np = negPart[(size_t)l * 8192 + i];
  }
  #pragma unroll
  for (int off = 1; off < 64; off <<= 1) {
    u64 a = __shfl_xor(pp, off);
    u64 b = __shfl_xor(np, off);
    pp = pp > a ? pp : a;
    np = np < b ? np : b;
  }
  int jp = (int)((0xFFFFFFFFu - (unsigned)(pp & 0xFFFFFFFFull)) & 8191u);
  int jn = (int)((unsigned)(np & 0xFFFFFFFFull) & 8191u);
  float2 a = *(const float2*)(E + (size_t)i * Dd + l * 2);
  float2 p = *(const float2*)(E + (size_t)jp * Dd + l * 2);
  float2 n = *(const float2*)(E + (size_t)jn * Dd + l * 2);
  float dx = a.x - p.x + EPSf, dy = a.y - p.y + EPSf;
  float sap = dx * dx + dy * dy;
  dx = a.x - n.x + EPSf;
  dy = a.y - n.y + EPSf;
  float san = dx * dx + dy * dy;
  #pragma unroll
  for (int off = 32; off; off >>= 1) {
    sap += __shfl_xor(sap, off);
    san += __shfl_xor(san, off);
  }
  if (l == 0) rowLoss[i] = fmaxf(sqrtf(sap) - sqrtf(san) + MARGINf, 0.0f);
}

// Deterministic tree reduction -> mean.
__global__ __launch_bounds__(256) void k_reduce(const float* __restrict__ rowLoss,
                                                float* __restrict__ out) {
  __shared__ float s[256];
  int t = threadIdx.x;
  float sum = 0.f;
  for (int q = 0; q < 32; ++q) sum += rowLoss[t + 256 * q];
  s[t] = sum;
  __syncthreads();
  for (int off = 128; off; off >>= 1) {
    if (t < off) s[t] += s[t + off];
    __syncthreads();
  }
  if (t == 0) out[0] = s[0] * (1.0f / 8192.0f);
}

extern "C" void kernel_launch(void* const* d_in, const int* in_sizes, int n_in,
                              void* d_out, int out_size, void* d_ws, size_t ws_size,
                              hipStream_t stream) {
  const float* E = (const float*)d_in[0];
  const int* lab = (const int*)d_in[1];
  float* out = (float*)d_out;

  char* wsp = (char*)d_ws;
  u64* posPart = (u64*)wsp;                         // 16*8192*8 = 1 MB
  u64* negPart = (u64*)(wsp + (1024 << 10));        // 1 MB
  float* normf = (float*)(wsp + (2048 << 10));      // 32 KB
  float* rowLoss = (float*)(wsp + (2080 << 10));    // 32 KB
  _Float16* Ehp = (_Float16*)(wsp + (2112 << 10));  // 2 MB packed frags

  k_prep<<<512, 256, 0, stream>>>(E, Ehp, normf);
  k_gemm<<<dim3(64, 8), 256, 0, stream>>>(Ehp, normf, lab, posPart, negPart);
  k_final<<<2048, 256, 0, stream>>>(E, posPart, negPart, rowLoss);
  k_reduce<<<1, 256, 0, stream>>>(rowLoss, out);
}